// Round 1
// 315.502 us; speedup vs baseline: 1.1656x; 1.1656x over previous
//
#include <hip/hip_runtime.h>
#include <math.h>

// Fused morphological opening: erode(10x10 flat, SAME) then dilate(10x10 flat,
// SAME), NHWC fp32 [16,512,512,8]. ONE kernel - the eroded intermediate lives
// entirely in LDS (previous best wrote it to a 128 MiB workspace and read it
// back: 2x the HBM traffic, 2 dispatches, 367 us).
//
// Decomposition per 31x32-px output tile (single LDS buffer, all passes
// in-place via read-stage -> barrier -> write):
//   P1 minV : global -> sA      40 rows (h0-4..h0+35) x 100 f4 (px w0-8..w0+41)
//   P2 minH : sA -> sA          40 rows x 82 f4       (eroded px w0-4..w0+36)
//   P3 maxV : sA -> sA          31 rows x 82 f4       (abs-row mask = -inf pad)
//   P4 maxH : sA -> sA          31 rows x 64 f4       (abs-px  mask = -inf pad)
//   P5 copy : sA -> global      coalesced, 1 KB per wave-store
// All four 1-D passes use the Gil-Werman run-of-8 trick: 17 taps -> 8 outputs
// (prefix L[] over taps 0..8, running suffix over taps 9..16).
// Boundary semantics (match lax.reduce_window SAME): erosion pads input +inf;
// dilation pads the *eroded image* -inf outside [0,512) - hence the abs-row /
// abs-px masks in P3/P4 (an eroded value computed at row -2 is finite but the
// reference treats it as -inf).
// LDS = 40*101*16 = 64,640 B -> 2 blocks/CU with 512 thr = 16 waves/CU (50%).
// Stride 101 f4 (odd) spreads row-strided ds_reads across banks (step 20).

#define W_F4   1024              // 512 px * 2 f4 (8 ch)
#define IMG_F4 (512 * W_F4)
#define TH     31                // output rows per tile
#define TW     32                // output px per tile
#define RA     40                // sA rows = TH + 9
#define CA     100               // minV cols (f4) = (TW + 18) * 2
#define S_A    101               // sA row stride (f4), odd
#define CB     82                // eroded cols (f4) = (TW + 9) * 2
#define NJ     41                // eroded px per row = TW + 9

__device__ __forceinline__ float4 f4min(float4 a, float4 b) {
    return make_float4(fminf(a.x,b.x), fminf(a.y,b.y), fminf(a.z,b.z), fminf(a.w,b.w));
}
__device__ __forceinline__ float4 f4max(float4 a, float4 b) {
    return make_float4(fmaxf(a.x,b.x), fmaxf(a.y,b.y), fmaxf(a.z,b.z), fmaxf(a.w,b.w));
}

__global__ __launch_bounds__(512, 4) void opening(const float4* __restrict__ in,
                                                  float4* __restrict__ out) {
    __shared__ float4 sA[RA * S_A];          // 64,640 B

    const float4 pinf4 = make_float4( INFINITY,  INFINITY,  INFINITY,  INFINITY);
    const float4 ninf4 = make_float4(-INFINITY, -INFINITY, -INFINITY, -INFINITY);

    const int t  = threadIdx.x;
    const int h0 = blockIdx.y * TH;          // last band ragged (h0 = 496)
    const int w0 = blockIdx.x * TW;

    const float4* img  = in  + (size_t)blockIdx.z * IMG_F4;
    float4*       oimg = out + (size_t)blockIdx.z * IMG_F4;

    // ---- P1: vertical min, global -> sA. 500 tasks: c in [0,100), run p in [0,5) ----
    // sA row s <-> abs row h0-4+s. 17 upfront global loads per task (latency ILP).
    if (t < 5 * CA) {
        const int c = t % CA;                // lanes = consecutive f4 cols (coalesced)
        const int p = t / CA;
        const int colf4 = w0 * 2 - 16 + c;
        const bool colok = (colf4 >= 0) & (colf4 < W_F4);

        float4 v[17];
#pragma unroll
        for (int q = 0; q < 17; q++) {       // input rows (h0-4) + (p*8+q) - 4
            int h = h0 + p * 8 + q - 8;
            bool ok = colok & (h >= 0) & (h < 512);
            v[q] = ok ? img[(size_t)h * W_F4 + colf4] : pinf4;
        }
        float4 L[9]; L[8] = v[8];
#pragma unroll
        for (int i = 7; i >= 0; i--) L[i] = f4min(v[i], L[i + 1]);
        float4 rr = v[9];
#pragma unroll
        for (int i = 0; i < 8; i++) {
            if (i > 0) rr = f4min(rr, v[9 + i]);
            sA[(p * 8 + i) * S_A + c] = f4min(L[i], rr);   // 5*8 = 40 rows exact
        }
    }
    __syncthreads();

    // ---- P2: horizontal min, sA -> sA in place. 480 tasks: c4 x 40 rows x 6 runs ----
    {
        const bool act = t < 2 * RA * 6;
        int base = 0, j0 = 0;
        float4 o8[8];
        if (act) {
            const int c4 = t & 1;
            const int r  = (t >> 1) % RA;
            j0 = ((t >> 1) / RA) * 8;        // output px j = j0+i, valid j < 41
            base = r * S_A + c4;
            // streamed taps: L over taps j0..j0+8 (k <= 48, always in range)
            float4 L[9]; L[8] = sA[base + 2 * (j0 + 8)];
#pragma unroll
            for (int i = 7; i >= 0; i--) L[i] = f4min(sA[base + 2 * (j0 + i)], L[i + 1]);
            float4 rr;
#pragma unroll
            for (int i = 0; i < 8; i++) {    // taps j0+9+i, guard k < 50
                int k = j0 + 9 + i;
                float4 tap = (k < 50) ? sA[base + 2 * k] : pinf4;
                rr = i ? f4min(rr, tap) : tap;
                o8[i] = f4min(L[i], rr);
            }
        }
        __syncthreads();                     // all P2 reads done before any write
        if (act) {
#pragma unroll
            for (int i = 0; i < 8; i++) {
                int j = j0 + i;
                if (j < NJ) sA[base + 2 * j] = o8[i];
            }
        }
    }
    __syncthreads();

    // ---- P3: vertical max, sA -> sA rows [0,31). 328 tasks: c in [0,82) x 4 runs ----
    // Tap valid iff eroded abs row h0-4+s in [0,512) (else -inf = dilation SAME pad).
    {
        const bool act = t < CB * 4;
        int c = 0, o0 = 0;
        float4 o8[8];
        if (act) {
            c  = t % CB;                     // lanes = consecutive f4 (conflict-free)
            o0 = (t / CB) * 8;               // output rows o0+i, valid o < 31
            float4 L[9];
#pragma unroll
            for (int i = 8; i >= 0; i--) {   // taps s = o0..o0+8 <= 32 (in range)
                int s = o0 + i;
                int h = h0 - 4 + s;
                float4 tap = ((h >= 0) & (h < 512)) ? sA[s * S_A + c] : ninf4;
                L[i] = (i == 8) ? tap : f4max(tap, L[i + 1]);
            }
            float4 rr;
#pragma unroll
            for (int i = 0; i < 8; i++) {    // taps s = o0+9+i, s=40 -> out of buf
                int s = o0 + 9 + i;
                int h = h0 - 4 + s;
                float4 tap = ((s < RA) & (h >= 0) & (h < 512)) ? sA[s * S_A + c] : ninf4;
                rr = i ? f4max(rr, tap) : tap;
                o8[i] = f4max(L[i], rr);
            }
        }
        __syncthreads();
        if (act) {
#pragma unroll
            for (int i = 0; i < 8; i++) {
                int o = o0 + i;
                if (o < TH) sA[o * S_A + c] = o8[i];
            }
        }
    }
    __syncthreads();

    // ---- P4: horizontal max, sA -> sA cols [0,64). 248 tasks: c4 x 31 rows x 4 runs ----
    // Tap valid iff eroded abs px w0-4+j in [0,512) (else -inf).
    {
        const bool act = t < 2 * TH * 4;
        int base = 0, x0 = 0;
        float4 o8[8];
        if (act) {
            const int c4 = t & 1;
            const int r  = (t >> 1) % TH;
            x0 = ((t >> 1) / TH) * 8;        // output px x0+i, 4*8 = 32 exact
            base = r * S_A + c4;
            float4 L[9];
#pragma unroll
            for (int i = 8; i >= 0; i--) {   // taps j = x0..x0+8 <= 32 (in range)
                int j = x0 + i;
                int px = w0 - 4 + j;
                float4 tap = ((px >= 0) & (px < 512)) ? sA[base + 2 * j] : ninf4;
                L[i] = (i == 8) ? tap : f4max(tap, L[i + 1]);
            }
            float4 rr;
#pragma unroll
            for (int i = 0; i < 8; i++) {    // taps j = x0+9+i <= 40 (in range)
                int j = x0 + 9 + i;
                int px = w0 - 4 + j;
                float4 tap = ((px >= 0) & (px < 512)) ? sA[base + 2 * j] : ninf4;
                rr = i ? f4max(rr, tap) : tap;
                o8[i] = f4max(L[i], rr);
            }
        }
        __syncthreads();
        if (act) {
#pragma unroll
            for (int i = 0; i < 8; i++)
                sA[base + 2 * (x0 + i)] = o8[i];
        }
    }
    __syncthreads();

    // ---- P5: coalesced copy sA -> global (lanes = consecutive f4, 1 KB/wave) ----
    for (int idx = t; idx < TH * 64; idx += 512) {
        int r = idx >> 6;
        int c = idx & 63;
        int h = h0 + r;
        if (h < 512)
            oimg[(size_t)h * W_F4 + (size_t)(w0 * 2 + c)] = sA[r * S_A + c];
    }
}

extern "C" void kernel_launch(void* const* d_in, const int* in_sizes, int n_in,
                              void* d_out, int out_size, void* d_ws, size_t ws_size,
                              hipStream_t stream) {
    const float4* in  = (const float4*)d_in[0];
    float4*       out = (float4*)d_out;
    (void)d_ws; (void)ws_size;               // workspace no longer needed

    dim3 grid(512 / TW, (512 + TH - 1) / TH, 16);   // 16 x 17 x 16 = 4352 blocks
    opening<<<grid, 512, 0, stream>>>(in, out);
}